// Round 6
// baseline (564.035 us; speedup 1.0000x reference)
//
#include <hip/hip_runtime.h>
#include <hip/hip_fp16.h>

#define NODES 50000
#define EDGES 800000
#define DIM 128
#define EPS_BN 1e-5f
#define SCAN_B 1024
#define SCAN_NB ((NODES + SCAN_B - 1) / SCAN_B)   // 49
#define GEMM_NB ((NODES + 127) / 128)             // 391
#define HB 32                                     // hist blocks
#define HT 1024                                   // hist threads
#define HRANGE ((NODES + HB - 1) / HB)            // 1563 nodes per block

// ---------------- LDS histogram: degrees + CSR slot (no global atomics) ----------------
// Block b owns node range [b*HRANGE, ...). All edges of an owned dst hit this
// block's LDS counter, so the LDS atomic return value is pos[e] directly.
__global__ __launch_bounds__(HT) void hist_kernel(const int* __restrict__ src,
                                                  const int* __restrict__ dst,
                                                  int* __restrict__ cnt_out,
                                                  int* __restrict__ cnt_in,
                                                  int* __restrict__ pos) {
    __shared__ int hsrc[HRANGE];
    __shared__ int hdst[HRANGE];
    int t = threadIdx.x;
    int base = blockIdx.x * HRANGE;
    int lim = min(HRANGE, NODES - base);
    for (int i = t; i < HRANGE; i += HT) { hsrc[i] = 0; hdst[i] = 0; }
    __syncthreads();
    for (int e = t; e < EDGES; e += HT) {
        int s = src[e];
        int d = dst[e];
        unsigned sr = (unsigned)(s - base);
        unsigned dr = (unsigned)(d - base);
        if (sr < (unsigned)lim) atomicAdd(&hsrc[sr], 1);
        if (dr < (unsigned)lim) pos[e] = atomicAdd(&hdst[dr], 1);
    }
    __syncthreads();
    for (int i = t; i < lim; i += HT) {
        cnt_out[base + i] = hsrc[i];
        cnt_in[base + i] = hdst[i];
    }
}

// ---------------- multi-block scan: phase 1 ----------------
__global__ __launch_bounds__(SCAN_B) void scan_p1_kernel(const int* __restrict__ cnt,
                                                         int* __restrict__ row_ptr,
                                                         int* __restrict__ blk_sums) {
    __shared__ int sm[SCAN_B];
    int t = threadIdx.x;
    int idx = blockIdx.x * SCAN_B + t;
    int v = (idx < NODES) ? cnt[idx] : 0;
    sm[t] = v;
    __syncthreads();
    #pragma unroll
    for (int off = 1; off < SCAN_B; off <<= 1) {
        int u = (t >= off) ? sm[t - off] : 0;
        __syncthreads();
        sm[t] += u;
        __syncthreads();
    }
    if (idx < NODES) row_ptr[idx] = sm[t] - v;
    if (t == SCAN_B - 1) blk_sums[blockIdx.x] = sm[t];
}

// ---------------- phase 2: wave-scan of block sums ----------------
__global__ __launch_bounds__(64) void scan_p2_kernel(const int* __restrict__ blk_sums,
                                                     int* __restrict__ blk_off) {
    int t = threadIdx.x;
    int orig = (t < SCAN_NB) ? blk_sums[t] : 0;
    int v = orig;
    #pragma unroll
    for (int off = 1; off < 64; off <<= 1) {
        int u = __shfl_up(v, off);
        if (t >= off) v += u;
    }
    if (t < SCAN_NB) blk_off[t] = v - orig;
}

// ---------------- phase 3: add block offsets + degree norms ----------------
__global__ __launch_bounds__(SCAN_B) void scan_p3_kernel(int* __restrict__ row_ptr,
                                                         const int* __restrict__ blk_off,
                                                         const int* __restrict__ cnt_out,
                                                         const int* __restrict__ cnt_in,
                                                         float* __restrict__ dn_out,
                                                         float* __restrict__ dn_in) {
    int t = threadIdx.x;
    int idx = blockIdx.x * SCAN_B + t;
    if (idx < NODES) {
        row_ptr[idx] += blk_off[blockIdx.x];
        dn_out[idx] = rsqrtf((float)max(cnt_out[idx], 1));
        dn_in[idx]  = rsqrtf((float)max(cnt_in[idx], 1));
    }
    if (idx == 0) row_ptr[NODES] = EDGES;
}

// ---------------- CSR fill (no atomics) ----------------
__global__ __launch_bounds__(256) void csr_fill_kernel(const int* __restrict__ src,
                                                       const int* __restrict__ dst,
                                                       const int* __restrict__ row_ptr,
                                                       const int* __restrict__ pos,
                                                       int* __restrict__ csr_src) {
    int e = blockIdx.x * 256 + threadIdx.x;
    if (e < EDGES) {
        csr_src[row_ptr[dst[e]] + pos[e]] = src[e];
    }
}

// ---------------- prescale to fp16: hs[i] = (half)(x[i] * dn_out[row]) ----------------
__global__ __launch_bounds__(256) void prescale_kernel(const float* __restrict__ x,
                                                       const float* __restrict__ dn_out,
                                                       __half* __restrict__ hs) {
    size_t idx = (size_t)blockIdx.x * 256 + threadIdx.x;   // over N*32 groups of 4
    if (idx >= (size_t)NODES * 32) return;
    int row = (int)(idx >> 5);
    float sc = dn_out[row];
    float4 v = *(const float4*)(x + idx * 4);
    __half2 a = __floats2half2_rn(v.x * sc, v.y * sc);
    __half2 b = __floats2half2_rn(v.z * sc, v.w * sc);
    float2 o;
    *(__half2*)&o.x = a;
    *(__half2*)&o.y = b;
    *(float2*)((char*)hs + idx * 8) = o;
}

// ---------------- pull aggregation over pre-scaled fp16 features ----------------
__device__ __forceinline__ void acc_h4(float2 raw, float& ax, float& ay, float& az, float& aw) {
    __half2 p0 = *(__half2*)&raw.x;
    __half2 p1 = *(__half2*)&raw.y;
    float2 f0 = __half22float2(p0);
    float2 f1 = __half22float2(p1);
    ax += f0.x; ay += f0.y; az += f1.x; aw += f1.y;
}

// agg output is fp16 (packed half2 x2 = 8B per lane)
__global__ __launch_bounds__(256) void pull_kernel(const __half* __restrict__ hs,
                                                   const int* __restrict__ row_ptr,
                                                   const int* __restrict__ csr_src,
                                                   const float* __restrict__ dn_in,
                                                   __half* __restrict__ agg) {
    int wid = threadIdx.x >> 6;
    int node = blockIdx.x * 4 + wid;
    if (node >= NODES) return;
    int lane = threadIdx.x & 63;
    int half = lane >> 5;
    int f4 = (lane & 31) * 4;
    const char* base = (const char*)hs;
    int beg = row_ptr[node];
    int end = row_ptr[node + 1];
    float ax = 0.f, ay = 0.f, az = 0.f, aw = 0.f;
    int e = beg + half;
    for (; e + 6 < end; e += 8) {
        int s0 = csr_src[e];
        int s1 = csr_src[e + 2];
        int s2 = csr_src[e + 4];
        int s3 = csr_src[e + 6];
        float2 r0 = *(const float2*)(base + ((size_t)s0 * DIM + f4) * 2);
        float2 r1 = *(const float2*)(base + ((size_t)s1 * DIM + f4) * 2);
        float2 r2 = *(const float2*)(base + ((size_t)s2 * DIM + f4) * 2);
        float2 r3 = *(const float2*)(base + ((size_t)s3 * DIM + f4) * 2);
        acc_h4(r0, ax, ay, az, aw);
        acc_h4(r1, ax, ay, az, aw);
        acc_h4(r2, ax, ay, az, aw);
        acc_h4(r3, ax, ay, az, aw);
    }
    for (; e < end; e += 2) {
        int s0 = csr_src[e];
        float2 r0 = *(const float2*)(base + ((size_t)s0 * DIM + f4) * 2);
        acc_h4(r0, ax, ay, az, aw);
    }
    ax += __shfl_xor(ax, 32);
    ay += __shfl_xor(ay, 32);
    az += __shfl_xor(az, 32);
    aw += __shfl_xor(aw, 32);
    if (half == 0) {
        float sc = dn_in[node];
        __half2 a = __floats2half2_rn(ax * sc, ay * sc);
        __half2 b = __floats2half2_rn(az * sc, aw * sc);
        float2 o;
        *(__half2*)&o.x = a;
        *(__half2*)&o.y = b;
        *(float2*)((char*)agg + ((size_t)node * DIM + f4) * 2) = o;
    }
}

// ---------------- GEMM (fp16 A) + fused BN partial stats ----------------
__global__ __launch_bounds__(256) void gemm_stats_kernel(const __half* __restrict__ A,
                                                         const float* __restrict__ W,
                                                         const float* __restrict__ bias,
                                                         float* __restrict__ out,
                                                         float* __restrict__ partial) {
    __shared__ float Ws[64 * DIM];
    __shared__ float As[64 * DIM];
    __shared__ float ps[2 * 16 * DIM];

    int t = threadIdx.x;
    int row0 = blockIdx.x * 128;
    int cg = t & 15;
    int rg = t >> 4;

    float acc[8][8];
    #pragma unroll
    for (int i = 0; i < 8; ++i)
        #pragma unroll
        for (int j = 0; j < 8; ++j) acc[i][j] = 0.f;

    int r = t >> 1;
    int kh = (t & 1) * 32;
    int grow = row0 + r;

    #pragma unroll
    for (int kt = 0; kt < DIM; kt += 64) {
        for (int i = t * 4; i < 64 * DIM; i += 1024)
            *(float4*)&Ws[i] = *(const float4*)&W[kt * DIM + i];
        if (grow < NODES) {
            const __half* ap = A + (size_t)grow * DIM + kt + kh;
            #pragma unroll
            for (int j = 0; j < 4; ++j) {
                float4 raw = *(const float4*)(ap + j * 8);   // 8 halves
                __half2* hp = (__half2*)&raw;
                #pragma unroll
                for (int q = 0; q < 4; ++q) {
                    float2 f = __half22float2(hp[q]);
                    As[(kh + j * 8 + q * 2 + 0) * DIM + r] = f.x;
                    As[(kh + j * 8 + q * 2 + 1) * DIM + r] = f.y;
                }
            }
        } else {
            #pragma unroll
            for (int j = 0; j < 32; ++j)
                As[(kh + j) * DIM + r] = 0.f;
        }
        __syncthreads();

        #pragma unroll 4
        for (int kk = 0; kk < 64; ++kk) {
            float4 a0 = *(float4*)&As[kk * DIM + rg * 8];
            float4 a1 = *(float4*)&As[kk * DIM + rg * 8 + 4];
            float4 w0 = *(float4*)&Ws[kk * DIM + cg * 8];
            float4 w1 = *(float4*)&Ws[kk * DIM + cg * 8 + 4];
            float av[8] = {a0.x, a0.y, a0.z, a0.w, a1.x, a1.y, a1.z, a1.w};
            float wv[8] = {w0.x, w0.y, w0.z, w0.w, w1.x, w1.y, w1.z, w1.w};
            #pragma unroll
            for (int i = 0; i < 8; ++i)
                #pragma unroll
                for (int j = 0; j < 8; ++j)
                    acc[i][j] += av[i] * wv[j];
        }
        __syncthreads();
    }

    float4 bv0 = *(const float4*)&bias[cg * 8];
    float4 bv1 = *(const float4*)&bias[cg * 8 + 4];
    float bb[8] = {bv0.x, bv0.y, bv0.z, bv0.w, bv1.x, bv1.y, bv1.z, bv1.w};
    float csum[8], csq[8];
    #pragma unroll
    for (int j = 0; j < 8; ++j) { csum[j] = 0.f; csq[j] = 0.f; }

    #pragma unroll
    for (int i = 0; i < 8; ++i) {
        int row = row0 + rg * 8 + i;
        if (row < NODES) {
            float o[8];
            #pragma unroll
            for (int j = 0; j < 8; ++j) {
                o[j] = acc[i][j] + bb[j];
                csum[j] += o[j];
                csq[j] += o[j] * o[j];
            }
            float4 o0 = {o[0], o[1], o[2], o[3]};
            float4 o1 = {o[4], o[5], o[6], o[7]};
            *(float4*)&out[(size_t)row * DIM + cg * 8] = o0;
            *(float4*)&out[(size_t)row * DIM + cg * 8 + 4] = o1;
        }
    }

    #pragma unroll
    for (int j = 0; j < 8; ++j) {
        ps[rg * DIM + cg * 8 + j] = csum[j];
        ps[16 * DIM + rg * DIM + cg * 8 + j] = csq[j];
    }
    __syncthreads();
    if (t < DIM) {
        float s = 0.f;
        #pragma unroll
        for (int g = 0; g < 16; ++g) s += ps[g * DIM + t];
        partial[(size_t)blockIdx.x * 256 + t] = s;
    } else {
        int c = t - DIM;
        float s = 0.f;
        #pragma unroll
        for (int g = 0; g < 16; ++g) s += ps[16 * DIM + g * DIM + c];
        partial[(size_t)blockIdx.x * 256 + DIM + c] = s;
    }
}

// ---------------- reduce per-block partials -> stats[256] ----------------
__global__ __launch_bounds__(256) void stats_reduce_kernel(const float* __restrict__ partial,
                                                           float* __restrict__ stats) {
    int t = threadIdx.x;
    float s = 0.f;
    for (int b = 0; b < GEMM_NB; ++b) s += partial[(size_t)b * 256 + t];
    stats[t] = s;
}

// ---------------- BN apply + ReLU; emit fp16 dn_out-scaled copy for next pull ----------------
__global__ __launch_bounds__(256) void bn_relu_scale_kernel(float* __restrict__ h,
                                                            __half* __restrict__ hs,
                                                            const float* __restrict__ stats,
                                                            const float* __restrict__ g,
                                                            const float* __restrict__ be,
                                                            const float* __restrict__ dn_out) {
    size_t idx = (size_t)blockIdx.x * 256 + threadIdx.x;
    if (idx >= (size_t)NODES * 32) return;
    int c = (int)(idx & 31) * 4;
    int row = (int)(idx >> 5);
    const float invN = 1.0f / NODES;
    float4 v = *(float4*)(h + idx * 4);
    float vv[4] = {v.x, v.y, v.z, v.w};
    float o[4];
    #pragma unroll
    for (int j = 0; j < 4; ++j) {
        float mu = stats[c + j] * invN;
        float var = stats[DIM + c + j] * invN - mu * mu;
        float w = g[c + j] * rsqrtf(var + EPS_BN);
        o[j] = fmaxf(w * (vv[j] - mu) + be[c + j], 0.f);
    }
    float4 r = {o[0], o[1], o[2], o[3]};
    *(float4*)(h + idx * 4) = r;
    float sc = dn_out[row];
    __half2 a = __floats2half2_rn(o[0] * sc, o[1] * sc);
    __half2 b = __floats2half2_rn(o[2] * sc, o[3] * sc);
    float2 rs;
    *(__half2*)&rs.x = a;
    *(__half2*)&rs.y = b;
    *(float2*)((char*)hs + idx * 8) = rs;
}

// ---------------- BN apply + residual + ReLU ----------------
__global__ __launch_bounds__(256) void bn_res_relu_kernel(float* __restrict__ out,
                                                          const float* __restrict__ h1,
                                                          const float* __restrict__ stats,
                                                          const float* __restrict__ g,
                                                          const float* __restrict__ be) {
    size_t idx = (size_t)blockIdx.x * 256 + threadIdx.x;
    if (idx >= (size_t)NODES * 32) return;
    int c = (int)(idx & 31) * 4;
    const float invN = 1.0f / NODES;
    float4 v = *(float4*)(out + idx * 4);
    float4 r1 = *(const float4*)(h1 + idx * 4);
    float vv[4] = {v.x, v.y, v.z, v.w};
    float rr[4] = {r1.x, r1.y, r1.z, r1.w};
    float o[4];
    #pragma unroll
    for (int j = 0; j < 4; ++j) {
        float mu = stats[c + j] * invN;
        float var = stats[DIM + c + j] * invN - mu * mu;
        float w = g[c + j] * rsqrtf(var + EPS_BN);
        o[j] = fmaxf(w * (vv[j] - mu) + be[c + j] + rr[j], 0.f);
    }
    float4 r = {o[0], o[1], o[2], o[3]};
    *(float4*)(out + idx * 4) = r;
}

extern "C" void kernel_launch(void* const* d_in, const int* in_sizes, int n_in,
                              void* d_out, int out_size, void* d_ws, size_t ws_size,
                              hipStream_t stream) {
    const float* x      = (const float*)d_in[0];
    const int*   src    = (const int*)d_in[1];
    const int*   dst    = (const int*)d_in[2];
    const float* W1     = (const float*)d_in[3];
    const float* b1     = (const float*)d_in[4];
    const float* gamma1 = (const float*)d_in[5];
    const float* beta1  = (const float*)d_in[6];
    const float* W2     = (const float*)d_in[7];
    const float* b2     = (const float*)d_in[8];
    const float* gamma2 = (const float*)d_in[9];
    const float* beta2  = (const float*)d_in[10];
    float* out = (float*)d_out;
    // fp16 pull-source scratch in d_out (12.8 MB of 25.6 MB; consumed by the
    // last pull before layer-2 gemm overwrites d_out).
    __half* hs = (__half*)d_out;

    // workspace (4B units): cnt_out[N] | cnt_in[N] | dn_out[N] | dn_in[N] |
    //   row_ptr[N+1] | pos[E] | csr_src[E] | stats[256] | blk[128] |
    //   partial[391*256] | agg_h[N*128 halves] | h1[N*128]
    char* wsc = (char*)d_ws;
    int*   cnt_out  = (int*)wsc;                     wsc += NODES * 4;
    int*   cnt_in   = (int*)wsc;                     wsc += NODES * 4;
    float* dn_out   = (float*)wsc;                   wsc += NODES * 4;
    float* dn_in    = (float*)wsc;                   wsc += NODES * 4;
    int*   row_ptr  = (int*)wsc;                     wsc += (NODES + 1) * 4;
    int*   pos      = (int*)wsc;                     wsc += EDGES * 4;
    int*   csr_src  = (int*)wsc;                     wsc += EDGES * 4;
    float* stats    = (float*)wsc;                   wsc += 2 * DIM * 4;
    int*   blk_sums = (int*)wsc;                     wsc += 64 * 4;
    int*   blk_off  = (int*)wsc;                     wsc += 64 * 4;
    float* partial  = (float*)wsc;                   wsc += (size_t)GEMM_NB * 256 * 4;
    __half* agg     = (__half*)wsc;                  wsc += (size_t)NODES * DIM * 2;
    float* h1       = (float*)wsc;

    const int T = 256;
    const int grid_e    = (EDGES + T - 1) / T;
    const int grid_pull = (NODES + 3) / 4;
    const int grid_elem = (NODES * 32 + T - 1) / T;

    // graph prep (no memsets needed: hist writes cnt arrays densely)
    hist_kernel<<<HB, HT, 0, stream>>>(src, dst, cnt_out, cnt_in, pos);
    scan_p1_kernel<<<SCAN_NB, SCAN_B, 0, stream>>>(cnt_in, row_ptr, blk_sums);
    scan_p2_kernel<<<1, 64, 0, stream>>>(blk_sums, blk_off);
    scan_p3_kernel<<<SCAN_NB, SCAN_B, 0, stream>>>(row_ptr, blk_off, cnt_out, cnt_in, dn_out, dn_in);
    csr_fill_kernel<<<grid_e, T, 0, stream>>>(src, dst, row_ptr, pos, csr_src);

    // layer 1
    prescale_kernel<<<grid_elem, T, 0, stream>>>(x, dn_out, hs);
    pull_kernel<<<grid_pull, T, 0, stream>>>(hs, row_ptr, csr_src, dn_in, agg);
    gemm_stats_kernel<<<GEMM_NB, T, 0, stream>>>(agg, W1, b1, h1, partial);
    stats_reduce_kernel<<<1, T, 0, stream>>>(partial, stats);
    bn_relu_scale_kernel<<<grid_elem, T, 0, stream>>>(h1, hs, stats, gamma1, beta1, dn_out);

    // layer 2
    pull_kernel<<<grid_pull, T, 0, stream>>>(hs, row_ptr, csr_src, dn_in, agg);
    gemm_stats_kernel<<<GEMM_NB, T, 0, stream>>>(agg, W2, b2, out, partial);
    stats_reduce_kernel<<<1, T, 0, stream>>>(partial, stats);
    bn_res_relu_kernel<<<grid_elem, T, 0, stream>>>(out, h1, stats, gamma2, beta2);
}

// Round 7
// 331.748 us; speedup vs baseline: 1.7002x; 1.7002x over previous
//
#include <hip/hip_runtime.h>
#include <hip/hip_fp16.h>

#define NODES 50000
#define EDGES 800000
#define DIM 128
#define EPS_BN 1e-5f
#define SCAN_B 1024
#define SCAN_NB ((NODES + SCAN_B - 1) / SCAN_B)   // 49
#define GEMM_NB ((NODES + 63) / 64)               // 782

typedef _Float16 half8 __attribute__((ext_vector_type(8)));
typedef float floatx4 __attribute__((ext_vector_type(4)));

// ---------------- degree histogram; cnt_in atomic return = CSR slot ----------------
__global__ __launch_bounds__(256) void degree_int_kernel(const int* __restrict__ src,
                                                         const int* __restrict__ dst,
                                                         int* __restrict__ cnt_out,
                                                         int* __restrict__ cnt_in,
                                                         int* __restrict__ pos) {
    int e = blockIdx.x * 256 + threadIdx.x;
    if (e < EDGES) {
        atomicAdd(&cnt_out[src[e]], 1);
        pos[e] = atomicAdd(&cnt_in[dst[e]], 1);
    }
}

// ---------------- multi-block scan: phase 1 ----------------
__global__ __launch_bounds__(SCAN_B) void scan_p1_kernel(const int* __restrict__ cnt,
                                                         int* __restrict__ row_ptr,
                                                         int* __restrict__ blk_sums) {
    __shared__ int sm[SCAN_B];
    int t = threadIdx.x;
    int idx = blockIdx.x * SCAN_B + t;
    int v = (idx < NODES) ? cnt[idx] : 0;
    sm[t] = v;
    __syncthreads();
    #pragma unroll
    for (int off = 1; off < SCAN_B; off <<= 1) {
        int u = (t >= off) ? sm[t - off] : 0;
        __syncthreads();
        sm[t] += u;
        __syncthreads();
    }
    if (idx < NODES) row_ptr[idx] = sm[t] - v;
    if (t == SCAN_B - 1) blk_sums[blockIdx.x] = sm[t];
}

// ---------------- phase 2: wave-scan of block sums ----------------
__global__ __launch_bounds__(64) void scan_p2_kernel(const int* __restrict__ blk_sums,
                                                     int* __restrict__ blk_off) {
    int t = threadIdx.x;
    int orig = (t < SCAN_NB) ? blk_sums[t] : 0;
    int v = orig;
    #pragma unroll
    for (int off = 1; off < 64; off <<= 1) {
        int u = __shfl_up(v, off);
        if (t >= off) v += u;
    }
    if (t < SCAN_NB) blk_off[t] = v - orig;
}

// ---------------- phase 3: add block offsets + degree norms ----------------
__global__ __launch_bounds__(SCAN_B) void scan_p3_kernel(int* __restrict__ row_ptr,
                                                         const int* __restrict__ blk_off,
                                                         const int* __restrict__ cnt_out,
                                                         const int* __restrict__ cnt_in,
                                                         float* __restrict__ dn_out,
                                                         float* __restrict__ dn_in) {
    int t = threadIdx.x;
    int idx = blockIdx.x * SCAN_B + t;
    if (idx < NODES) {
        row_ptr[idx] += blk_off[blockIdx.x];
        dn_out[idx] = rsqrtf((float)max(cnt_out[idx], 1));
        dn_in[idx]  = rsqrtf((float)max(cnt_in[idx], 1));
    }
    if (idx == 0) row_ptr[NODES] = EDGES;
}

// ---------------- CSR fill (no atomics) ----------------
__global__ __launch_bounds__(256) void csr_fill_kernel(const int* __restrict__ src,
                                                       const int* __restrict__ dst,
                                                       const int* __restrict__ row_ptr,
                                                       const int* __restrict__ pos,
                                                       int* __restrict__ csr_src) {
    int e = blockIdx.x * 256 + threadIdx.x;
    if (e < EDGES) {
        csr_src[row_ptr[dst[e]] + pos[e]] = src[e];
    }
}

// ---------------- W fp32 -> WhT fp16 transposed ----------------
__global__ __launch_bounds__(256) void w2h_kernel(const float* __restrict__ W,
                                                  __half* __restrict__ WhT) {
    int idx = blockIdx.x * 256 + threadIdx.x;   // 16384 total
    int n = idx >> 7;
    int k = idx & 127;
    WhT[idx] = __float2half(W[k * DIM + n]);    // WhT[n][k] = W[k][n]
}

// ---------------- prescale to fp16: hs[i] = (half)(x[i] * dn_out[row]) ----------------
__global__ __launch_bounds__(256) void prescale_kernel(const float* __restrict__ x,
                                                       const float* __restrict__ dn_out,
                                                       __half* __restrict__ hs) {
    size_t idx = (size_t)blockIdx.x * 256 + threadIdx.x;
    if (idx >= (size_t)NODES * 32) return;
    int row = (int)(idx >> 5);
    float sc = dn_out[row];
    float4 v = *(const float4*)(x + idx * 4);
    __half2 a = __floats2half2_rn(v.x * sc, v.y * sc);
    __half2 b = __floats2half2_rn(v.z * sc, v.w * sc);
    float2 o;
    *(__half2*)&o.x = a;
    *(__half2*)&o.y = b;
    *(float2*)((char*)hs + idx * 8) = o;
}

// ---------------- pull aggregation over pre-scaled fp16 features ----------------
__device__ __forceinline__ void acc_h4(float2 raw, float& ax, float& ay, float& az, float& aw) {
    __half2 p0 = *(__half2*)&raw.x;
    __half2 p1 = *(__half2*)&raw.y;
    float2 f0 = __half22float2(p0);
    float2 f1 = __half22float2(p1);
    ax += f0.x; ay += f0.y; az += f1.x; aw += f1.y;
}

__global__ __launch_bounds__(256) void pull_kernel(const __half* __restrict__ hs,
                                                   const int* __restrict__ row_ptr,
                                                   const int* __restrict__ csr_src,
                                                   const float* __restrict__ dn_in,
                                                   __half* __restrict__ agg) {
    int wid = threadIdx.x >> 6;
    int node = blockIdx.x * 4 + wid;
    if (node >= NODES) return;
    int lane = threadIdx.x & 63;
    int half = lane >> 5;
    int f4 = (lane & 31) * 4;
    const char* base = (const char*)hs;
    int beg = row_ptr[node];
    int end = row_ptr[node + 1];
    float ax = 0.f, ay = 0.f, az = 0.f, aw = 0.f;
    int e = beg + half;
    for (; e + 6 < end; e += 8) {
        int s0 = csr_src[e];
        int s1 = csr_src[e + 2];
        int s2 = csr_src[e + 4];
        int s3 = csr_src[e + 6];
        float2 r0 = *(const float2*)(base + ((size_t)s0 * DIM + f4) * 2);
        float2 r1 = *(const float2*)(base + ((size_t)s1 * DIM + f4) * 2);
        float2 r2 = *(const float2*)(base + ((size_t)s2 * DIM + f4) * 2);
        float2 r3 = *(const float2*)(base + ((size_t)s3 * DIM + f4) * 2);
        acc_h4(r0, ax, ay, az, aw);
        acc_h4(r1, ax, ay, az, aw);
        acc_h4(r2, ax, ay, az, aw);
        acc_h4(r3, ax, ay, az, aw);
    }
    for (; e < end; e += 2) {
        int s0 = csr_src[e];
        float2 r0 = *(const float2*)(base + ((size_t)s0 * DIM + f4) * 2);
        acc_h4(r0, ax, ay, az, aw);
    }
    ax += __shfl_xor(ax, 32);
    ay += __shfl_xor(ay, 32);
    az += __shfl_xor(az, 32);
    aw += __shfl_xor(aw, 32);
    if (half == 0) {
        float sc = dn_in[node];
        __half2 a = __floats2half2_rn(ax * sc, ay * sc);
        __half2 b = __floats2half2_rn(az * sc, aw * sc);
        float2 o;
        *(__half2*)&o.x = a;
        *(__half2*)&o.y = b;
        *(float2*)((char*)agg + ((size_t)node * DIM + f4) * 2) = o;
    }
}

// ---------------- MFMA GEMM (fp16 A, fp16 W^T) + fused BN partial stats ----------------
// 64 rows/block, 256 threads = 4 waves x 16 rows. 8 col-tiles x 4 k-steps of
// v_mfma_f32_16x16x32_f16. WhT staged in LDS with 136-half row stride
// (balanced banks for b-frag ds_read_b128). LDS reused for stats scratch.
__global__ __launch_bounds__(256) void gemm_mfma_kernel(const __half* __restrict__ A,
                                                        const __half* __restrict__ WhT,
                                                        const float* __restrict__ bias,
                                                        float* __restrict__ out,
                                                        float* __restrict__ partial) {
    __shared__ float smem[8704];          // 34816 B >= max(WhT_lds 34816, ps 16384)
    __half* wl = (__half*)smem;

    int t = threadIdx.x;

    // stage WhT[128][128] -> LDS rows of stride 136 halves (272 B, 16B-aligned)
    #pragma unroll
    for (int i = 0; i < 8; ++i) {
        int c = t + 256 * i;              // 2048 chunks of 16 B
        int n = c >> 4;
        int ch = c & 15;
        *(float4*)((char*)wl + n * 272 + ch * 16) =
            *(const float4*)((const char*)WhT + n * 256 + ch * 16);
    }

    int w = t >> 6;
    int lane = t & 63;
    int m = lane & 15;
    int quad = lane >> 4;
    int r0 = blockIdx.x * 64 + w * 16;
    int arow = r0 + m;

    // A-fragments for all 4 k-steps: A[m=lane&15][k = kt*32 + quad*8 + j]
    half8 afrag[4];
    if (arow < NODES) {
        const char* ap = (const char*)(A + (size_t)arow * DIM);
        #pragma unroll
        for (int kt = 0; kt < 4; ++kt)
            afrag[kt] = *(const half8*)(ap + kt * 64 + quad * 16);
    } else {
        #pragma unroll
        for (int kt = 0; kt < 4; ++kt)
            #pragma unroll
            for (int j = 0; j < 8; ++j)
                afrag[kt][j] = (_Float16)0.0f;
    }

    floatx4 acc[8];
    floatx4 zf = {0.f, 0.f, 0.f, 0.f};
    #pragma unroll
    for (int ct = 0; ct < 8; ++ct) acc[ct] = zf;

    __syncthreads();

    #pragma unroll
    for (int kt = 0; kt < 4; ++kt) {
        #pragma unroll
        for (int ct = 0; ct < 8; ++ct) {
            // b-frag: WhT[n = ct*16 + (lane&15)][k = kt*32 + quad*8 + j]
            half8 b = *(const half8*)((const char*)wl + (ct * 16 + m) * 272 + kt * 64 + quad * 16);
            acc[ct] = __builtin_amdgcn_mfma_f32_16x16x32_f16(afrag[kt], b, acc[ct], 0, 0, 0);
        }
    }

    __syncthreads();   // done reading WhT; smem becomes stats scratch

    float* ps = smem;  // ps_sum[16][128] | ps_sq[16][128]
    int g = w * 4 + quad;
    #pragma unroll
    for (int ct = 0; ct < 8; ++ct) {
        int col = ct * 16 + m;
        float bb = bias[col];
        float cs = 0.f, cq = 0.f;
        #pragma unroll
        for (int reg = 0; reg < 4; ++reg) {
            int row = r0 + quad * 4 + reg;   // C/D: row = quad*4 + reg, col = lane&15
            if (row < NODES) {
                float o = acc[ct][reg] + bb;
                out[(size_t)row * DIM + col] = o;
                cs += o;
                cq += o * o;
            }
        }
        ps[g * 128 + col] = cs;
        ps[2048 + g * 128 + col] = cq;
    }
    __syncthreads();

    if (t < 128) {
        float s = 0.f;
        #pragma unroll
        for (int gg = 0; gg < 16; ++gg) s += ps[gg * 128 + t];
        partial[(size_t)blockIdx.x * 256 + t] = s;
    } else {
        int c = t - 128;
        float s = 0.f;
        #pragma unroll
        for (int gg = 0; gg < 16; ++gg) s += ps[2048 + gg * 128 + c];
        partial[(size_t)blockIdx.x * 256 + 128 + c] = s;
    }
}

// ---------------- two-stage partial reduction -> stats[256] ----------------
__global__ __launch_bounds__(256) void stats_s1_kernel(const float* __restrict__ partial,
                                                       float* __restrict__ p2) {
    int t = threadIdx.x;
    float s = 0.f;
    for (int b = blockIdx.x; b < GEMM_NB; b += 32) s += partial[(size_t)b * 256 + t];
    p2[blockIdx.x * 256 + t] = s;
}

__global__ __launch_bounds__(256) void stats_s2_kernel(const float* __restrict__ p2,
                                                       float* __restrict__ stats) {
    int t = threadIdx.x;
    float s = 0.f;
    #pragma unroll
    for (int b = 0; b < 32; ++b) s += p2[b * 256 + t];
    stats[t] = s;
}

// ---------------- BN apply + ReLU; emit fp16 dn_out-scaled copy for next pull ----------------
__global__ __launch_bounds__(256) void bn_relu_scale_kernel(float* __restrict__ h,
                                                            __half* __restrict__ hs,
                                                            const float* __restrict__ stats,
                                                            const float* __restrict__ g,
                                                            const float* __restrict__ be,
                                                            const float* __restrict__ dn_out) {
    size_t idx = (size_t)blockIdx.x * 256 + threadIdx.x;
    if (idx >= (size_t)NODES * 32) return;
    int c = (int)(idx & 31) * 4;
    int row = (int)(idx >> 5);
    const float invN = 1.0f / NODES;
    float4 v = *(float4*)(h + idx * 4);
    float vv[4] = {v.x, v.y, v.z, v.w};
    float o[4];
    #pragma unroll
    for (int j = 0; j < 4; ++j) {
        float mu = stats[c + j] * invN;
        float var = stats[DIM + c + j] * invN - mu * mu;
        float w = g[c + j] * rsqrtf(var + EPS_BN);
        o[j] = fmaxf(w * (vv[j] - mu) + be[c + j], 0.f);
    }
    float4 r = {o[0], o[1], o[2], o[3]};
    *(float4*)(h + idx * 4) = r;
    float sc = dn_out[row];
    __half2 a = __floats2half2_rn(o[0] * sc, o[1] * sc);
    __half2 b = __floats2half2_rn(o[2] * sc, o[3] * sc);
    float2 rs;
    *(__half2*)&rs.x = a;
    *(__half2*)&rs.y = b;
    *(float2*)((char*)hs + idx * 8) = rs;
}

// ---------------- BN apply + residual + ReLU ----------------
__global__ __launch_bounds__(256) void bn_res_relu_kernel(float* __restrict__ out,
                                                          const float* __restrict__ h1,
                                                          const float* __restrict__ stats,
                                                          const float* __restrict__ g,
                                                          const float* __restrict__ be) {
    size_t idx = (size_t)blockIdx.x * 256 + threadIdx.x;
    if (idx >= (size_t)NODES * 32) return;
    int c = (int)(idx & 31) * 4;
    const float invN = 1.0f / NODES;
    float4 v = *(float4*)(out + idx * 4);
    float4 r1 = *(const float4*)(h1 + idx * 4);
    float vv[4] = {v.x, v.y, v.z, v.w};
    float rr[4] = {r1.x, r1.y, r1.z, r1.w};
    float o[4];
    #pragma unroll
    for (int j = 0; j < 4; ++j) {
        float mu = stats[c + j] * invN;
        float var = stats[DIM + c + j] * invN - mu * mu;
        float w = g[c + j] * rsqrtf(var + EPS_BN);
        o[j] = fmaxf(w * (vv[j] - mu) + be[c + j] + rr[j], 0.f);
    }
    float4 r = {o[0], o[1], o[2], o[3]};
    *(float4*)(out + idx * 4) = r;
}

extern "C" void kernel_launch(void* const* d_in, const int* in_sizes, int n_in,
                              void* d_out, int out_size, void* d_ws, size_t ws_size,
                              hipStream_t stream) {
    const float* x      = (const float*)d_in[0];
    const int*   src    = (const int*)d_in[1];
    const int*   dst    = (const int*)d_in[2];
    const float* W1     = (const float*)d_in[3];
    const float* b1     = (const float*)d_in[4];
    const float* gamma1 = (const float*)d_in[5];
    const float* beta1  = (const float*)d_in[6];
    const float* W2     = (const float*)d_in[7];
    const float* b2     = (const float*)d_in[8];
    const float* gamma2 = (const float*)d_in[9];
    const float* beta2  = (const float*)d_in[10];
    float* out = (float*)d_out;
    // fp16 pull-source scratch in d_out (12.8 MB of 25.6 MB; consumed by the
    // last pull before layer-2 gemm overwrites d_out).
    __half* hs = (__half*)d_out;

    char* wsc = (char*)d_ws;
    int*   cnt_out  = (int*)wsc;                     wsc += NODES * 4;
    int*   cnt_in   = (int*)wsc;                     wsc += NODES * 4;
    float* dn_out   = (float*)wsc;                   wsc += NODES * 4;
    float* dn_in    = (float*)wsc;                   wsc += NODES * 4;
    int*   row_ptr  = (int*)wsc;                     wsc += (NODES + 1) * 4;
    int*   pos      = (int*)wsc;                     wsc += EDGES * 4;
    int*   csr_src  = (int*)wsc;                     wsc += EDGES * 4;
    float* stats    = (float*)wsc;                   wsc += 2 * DIM * 4;
    int*   blk_sums = (int*)wsc;                     wsc += 64 * 4;
    int*   blk_off  = (int*)wsc;                     wsc += 64 * 4;
    __half* WhT1    = (__half*)wsc;                  wsc += DIM * DIM * 2;
    __half* WhT2    = (__half*)wsc;                  wsc += DIM * DIM * 2;
    float* partial  = (float*)wsc;                   wsc += (size_t)GEMM_NB * 256 * 4;
    float* p2       = (float*)wsc;                   wsc += 32 * 256 * 4;
    __half* agg     = (__half*)wsc;                  wsc += (size_t)NODES * DIM * 2;
    float* h1       = (float*)wsc;

    const int T = 256;
    const int grid_e    = (EDGES + T - 1) / T;
    const int grid_pull = (NODES + 3) / 4;
    const int grid_elem = (NODES * 32 + T - 1) / T;

    hipMemsetAsync(cnt_out, 0, 2 * NODES * 4, stream);

    // graph prep
    degree_int_kernel<<<grid_e, T, 0, stream>>>(src, dst, cnt_out, cnt_in, pos);
    scan_p1_kernel<<<SCAN_NB, SCAN_B, 0, stream>>>(cnt_in, row_ptr, blk_sums);
    scan_p2_kernel<<<1, 64, 0, stream>>>(blk_sums, blk_off);
    scan_p3_kernel<<<SCAN_NB, SCAN_B, 0, stream>>>(row_ptr, blk_off, cnt_out, cnt_in, dn_out, dn_in);
    csr_fill_kernel<<<grid_e, T, 0, stream>>>(src, dst, row_ptr, pos, csr_src);

    // weight conversion (fp32 -> fp16 transposed)
    w2h_kernel<<<64, T, 0, stream>>>(W1, WhT1);
    w2h_kernel<<<64, T, 0, stream>>>(W2, WhT2);

    // layer 1
    prescale_kernel<<<grid_elem, T, 0, stream>>>(x, dn_out, hs);
    pull_kernel<<<grid_pull, T, 0, stream>>>(hs, row_ptr, csr_src, dn_in, agg);
    gemm_mfma_kernel<<<GEMM_NB, T, 0, stream>>>(agg, WhT1, b1, h1, partial);
    stats_s1_kernel<<<32, T, 0, stream>>>(partial, p2);
    stats_s2_kernel<<<1, T, 0, stream>>>(p2, stats);
    bn_relu_scale_kernel<<<grid_elem, T, 0, stream>>>(h1, hs, stats, gamma1, beta1, dn_out);

    // layer 2
    pull_kernel<<<grid_pull, T, 0, stream>>>(hs, row_ptr, csr_src, dn_in, agg);
    gemm_mfma_kernel<<<GEMM_NB, T, 0, stream>>>(agg, WhT2, b2, out, partial);
    stats_s1_kernel<<<32, T, 0, stream>>>(partial, p2);
    stats_s2_kernel<<<1, T, 0, stream>>>(p2, stats);
    bn_res_relu_kernel<<<grid_elem, T, 0, stream>>>(out, h1, stats, gamma2, beta2);
}

// Round 8
// 299.921 us; speedup vs baseline: 1.8806x; 1.1061x over previous
//
#include <hip/hip_runtime.h>
#include <hip/hip_fp16.h>

#define NODES 50000
#define EDGES 800000
#define DIM 128
#define EPS_BN 1e-5f
#define SCAN_B 1024
#define SCAN_NB ((NODES + SCAN_B - 1) / SCAN_B)   // 49
#define GEMM_NB ((NODES + 63) / 64)               // 782
#define NCH 64                                    // edge chunks
#define CHE (EDGES / NCH)                         // 12500 edges/chunk
#define NR 4                                      // node ranges
#define RNG (NODES / NR)                          // 12500 nodes/range

typedef _Float16 half8 __attribute__((ext_vector_type(8)));
typedef float floatx4 __attribute__((ext_vector_type(4)));

// ---------------- pass 1: partial LDS histograms (no global atomics) ----------------
// grid (NR*NCH, 2): y=0 histograms src, y=1 histograms dst.
__global__ __launch_bounds__(256) void hist_part_kernel(const int* __restrict__ src,
                                                        const int* __restrict__ dst,
                                                        unsigned short* __restrict__ Psrc,
                                                        unsigned short* __restrict__ Pdst) {
    __shared__ int h[RNG];   // 50 KB
    int chunk = blockIdx.x & (NCH - 1);
    int range = blockIdx.x >> 6;
    const int* arr = blockIdx.y ? dst : src;
    unsigned short* P = blockIdx.y ? Pdst : Psrc;
    int base = range * RNG;
    for (int i = threadIdx.x; i < RNG; i += 256) h[i] = 0;
    __syncthreads();
    int e0 = chunk * CHE;
    for (int e = e0 + threadIdx.x; e < e0 + CHE; e += 256) {
        unsigned r = (unsigned)(arr[e] - base);
        if (r < (unsigned)RNG) atomicAdd(&h[r], 1);
    }
    __syncthreads();
    for (int i = threadIdx.x; i < RNG; i += 256)
        P[(size_t)chunk * NODES + base + i] = (unsigned short)h[i];
}

// ---------------- pass 2: sum Psrc -> dn_out; scan Pdst in place -> bases, cnt_in ----
__global__ __launch_bounds__(256) void combine_kernel(const unsigned short* __restrict__ Psrc,
                                                      unsigned short* __restrict__ Pdst,
                                                      int* __restrict__ cnt_in,
                                                      float* __restrict__ dn_out,
                                                      float* __restrict__ dn_in) {
    int v = blockIdx.x * 256 + threadIdx.x;
    if (v >= NODES) return;
    int s = 0;
    #pragma unroll 8
    for (int j = 0; j < NCH; ++j) s += Psrc[(size_t)j * NODES + v];
    dn_out[v] = rsqrtf((float)max(s, 1));
    int run = 0;
    for (int j = 0; j < NCH; ++j) {
        int t = Pdst[(size_t)j * NODES + v];
        Pdst[(size_t)j * NODES + v] = (unsigned short)run;
        run += t;
    }
    cnt_in[v] = run;
    dn_in[v] = rsqrtf((float)max(run, 1));
}

// ---------------- row_ptr scan over cnt_in ----------------
__global__ __launch_bounds__(SCAN_B) void scan_p1_kernel(const int* __restrict__ cnt,
                                                         int* __restrict__ row_ptr,
                                                         int* __restrict__ blk_sums) {
    __shared__ int sm[SCAN_B];
    int t = threadIdx.x;
    int idx = blockIdx.x * SCAN_B + t;
    int v = (idx < NODES) ? cnt[idx] : 0;
    sm[t] = v;
    __syncthreads();
    #pragma unroll
    for (int off = 1; off < SCAN_B; off <<= 1) {
        int u = (t >= off) ? sm[t - off] : 0;
        __syncthreads();
        sm[t] += u;
        __syncthreads();
    }
    if (idx < NODES) row_ptr[idx] = sm[t] - v;
    if (t == SCAN_B - 1) blk_sums[blockIdx.x] = sm[t];
}

__global__ __launch_bounds__(64) void scan_p2_kernel(const int* __restrict__ blk_sums,
                                                     int* __restrict__ blk_off) {
    int t = threadIdx.x;
    int orig = (t < SCAN_NB) ? blk_sums[t] : 0;
    int v = orig;
    #pragma unroll
    for (int off = 1; off < 64; off <<= 1) {
        int u = __shfl_up(v, off);
        if (t >= off) v += u;
    }
    if (t < SCAN_NB) blk_off[t] = v - orig;
}

__global__ __launch_bounds__(SCAN_B) void scan_p3_kernel(int* __restrict__ row_ptr,
                                                         const int* __restrict__ blk_off) {
    int t = threadIdx.x;
    int idx = blockIdx.x * SCAN_B + t;
    if (idx < NODES) row_ptr[idx] += blk_off[blockIdx.x];
    if (idx == 0) row_ptr[NODES] = EDGES;
}

// ---------------- pass 3: CSR fill via local re-histogram (no global atomics) -------
__global__ __launch_bounds__(256) void fill_kernel(const int* __restrict__ src,
                                                   const int* __restrict__ dst,
                                                   const int* __restrict__ row_ptr,
                                                   const unsigned short* __restrict__ Pdst,
                                                   int* __restrict__ csr_src) {
    __shared__ int h[RNG];   // 50 KB
    int chunk = blockIdx.x & (NCH - 1);
    int range = blockIdx.x >> 6;
    int base = range * RNG;
    for (int i = threadIdx.x; i < RNG; i += 256) h[i] = 0;
    __syncthreads();
    int e0 = chunk * CHE;
    const unsigned short* Pj = Pdst + (size_t)chunk * NODES;
    for (int e = e0 + threadIdx.x; e < e0 + CHE; e += 256) {
        int d = dst[e];
        unsigned r = (unsigned)(d - base);
        if (r < (unsigned)RNG) {
            int local = atomicAdd(&h[r], 1);   // LDS atomic only
            csr_src[row_ptr[d] + (int)Pj[d] + local] = src[e];
        }
    }
}

// ---------------- W fp32 -> WhT fp16 transposed ----------------
__global__ __launch_bounds__(256) void w2h_kernel(const float* __restrict__ W,
                                                  __half* __restrict__ WhT) {
    int idx = blockIdx.x * 256 + threadIdx.x;
    int n = idx >> 7;
    int k = idx & 127;
    WhT[idx] = __float2half(W[k * DIM + n]);
}

// ---------------- prescale to fp16 ----------------
__global__ __launch_bounds__(256) void prescale_kernel(const float* __restrict__ x,
                                                       const float* __restrict__ dn_out,
                                                       __half* __restrict__ hs) {
    size_t idx = (size_t)blockIdx.x * 256 + threadIdx.x;
    if (idx >= (size_t)NODES * 32) return;
    int row = (int)(idx >> 5);
    float sc = dn_out[row];
    float4 v = *(const float4*)(x + idx * 4);
    __half2 a = __floats2half2_rn(v.x * sc, v.y * sc);
    __half2 b = __floats2half2_rn(v.z * sc, v.w * sc);
    float2 o;
    *(__half2*)&o.x = a;
    *(__half2*)&o.y = b;
    *(float2*)((char*)hs + idx * 8) = o;
}

// ---------------- pull aggregation over pre-scaled fp16 features ----------------
__device__ __forceinline__ void acc_h4(float2 raw, float& ax, float& ay, float& az, float& aw) {
    __half2 p0 = *(__half2*)&raw.x;
    __half2 p1 = *(__half2*)&raw.y;
    float2 f0 = __half22float2(p0);
    float2 f1 = __half22float2(p1);
    ax += f0.x; ay += f0.y; az += f1.x; aw += f1.y;
}

__global__ __launch_bounds__(256) void pull_kernel(const __half* __restrict__ hs,
                                                   const int* __restrict__ row_ptr,
                                                   const int* __restrict__ csr_src,
                                                   const float* __restrict__ dn_in,
                                                   __half* __restrict__ agg) {
    int wid = threadIdx.x >> 6;
    int node = blockIdx.x * 4 + wid;
    if (node >= NODES) return;
    int lane = threadIdx.x & 63;
    int half = lane >> 5;
    int f4 = (lane & 31) * 4;
    const char* base = (const char*)hs;
    int beg = row_ptr[node];
    int end = row_ptr[node + 1];
    float ax = 0.f, ay = 0.f, az = 0.f, aw = 0.f;
    int e = beg + half;
    for (; e + 6 < end; e += 8) {
        int s0 = csr_src[e];
        int s1 = csr_src[e + 2];
        int s2 = csr_src[e + 4];
        int s3 = csr_src[e + 6];
        float2 r0 = *(const float2*)(base + ((size_t)s0 * DIM + f4) * 2);
        float2 r1 = *(const float2*)(base + ((size_t)s1 * DIM + f4) * 2);
        float2 r2 = *(const float2*)(base + ((size_t)s2 * DIM + f4) * 2);
        float2 r3 = *(const float2*)(base + ((size_t)s3 * DIM + f4) * 2);
        acc_h4(r0, ax, ay, az, aw);
        acc_h4(r1, ax, ay, az, aw);
        acc_h4(r2, ax, ay, az, aw);
        acc_h4(r3, ax, ay, az, aw);
    }
    for (; e < end; e += 2) {
        int s0 = csr_src[e];
        float2 r0 = *(const float2*)(base + ((size_t)s0 * DIM + f4) * 2);
        acc_h4(r0, ax, ay, az, aw);
    }
    ax += __shfl_xor(ax, 32);
    ay += __shfl_xor(ay, 32);
    az += __shfl_xor(az, 32);
    aw += __shfl_xor(aw, 32);
    if (half == 0) {
        float sc = dn_in[node];
        __half2 a = __floats2half2_rn(ax * sc, ay * sc);
        __half2 b = __floats2half2_rn(az * sc, aw * sc);
        float2 o;
        *(__half2*)&o.x = a;
        *(__half2*)&o.y = b;
        *(float2*)((char*)agg + ((size_t)node * DIM + f4) * 2) = o;
    }
}

// ---------------- MFMA GEMM (fp16 A, fp16 W^T) + fused BN partial stats ----------------
__global__ __launch_bounds__(256) void gemm_mfma_kernel(const __half* __restrict__ A,
                                                        const __half* __restrict__ WhT,
                                                        const float* __restrict__ bias,
                                                        float* __restrict__ out,
                                                        float* __restrict__ partial) {
    __shared__ float smem[8704];
    __half* wl = (__half*)smem;

    int t = threadIdx.x;

    #pragma unroll
    for (int i = 0; i < 8; ++i) {
        int c = t + 256 * i;
        int n = c >> 4;
        int ch = c & 15;
        *(float4*)((char*)wl + n * 272 + ch * 16) =
            *(const float4*)((const char*)WhT + n * 256 + ch * 16);
    }

    int w = t >> 6;
    int lane = t & 63;
    int m = lane & 15;
    int quad = lane >> 4;
    int r0 = blockIdx.x * 64 + w * 16;
    int arow = r0 + m;

    half8 afrag[4];
    if (arow < NODES) {
        const char* ap = (const char*)(A + (size_t)arow * DIM);
        #pragma unroll
        for (int kt = 0; kt < 4; ++kt)
            afrag[kt] = *(const half8*)(ap + kt * 64 + quad * 16);
    } else {
        #pragma unroll
        for (int kt = 0; kt < 4; ++kt)
            #pragma unroll
            for (int j = 0; j < 8; ++j)
                afrag[kt][j] = (_Float16)0.0f;
    }

    floatx4 acc[8];
    floatx4 zf = {0.f, 0.f, 0.f, 0.f};
    #pragma unroll
    for (int ct = 0; ct < 8; ++ct) acc[ct] = zf;

    __syncthreads();

    #pragma unroll
    for (int kt = 0; kt < 4; ++kt) {
        #pragma unroll
        for (int ct = 0; ct < 8; ++ct) {
            half8 b = *(const half8*)((const char*)wl + (ct * 16 + m) * 272 + kt * 64 + quad * 16);
            acc[ct] = __builtin_amdgcn_mfma_f32_16x16x32_f16(afrag[kt], b, acc[ct], 0, 0, 0);
        }
    }

    __syncthreads();

    float* ps = smem;
    int g = w * 4 + quad;
    #pragma unroll
    for (int ct = 0; ct < 8; ++ct) {
        int col = ct * 16 + m;
        float bb = bias[col];
        float cs = 0.f, cq = 0.f;
        #pragma unroll
        for (int reg = 0; reg < 4; ++reg) {
            int row = r0 + quad * 4 + reg;
            if (row < NODES) {
                float o = acc[ct][reg] + bb;
                out[(size_t)row * DIM + col] = o;
                cs += o;
                cq += o * o;
            }
        }
        ps[g * 128 + col] = cs;
        ps[2048 + g * 128 + col] = cq;
    }
    __syncthreads();

    if (t < 128) {
        float s = 0.f;
        #pragma unroll
        for (int gg = 0; gg < 16; ++gg) s += ps[gg * 128 + t];
        partial[(size_t)blockIdx.x * 256 + t] = s;
    } else {
        int c = t - 128;
        float s = 0.f;
        #pragma unroll
        for (int gg = 0; gg < 16; ++gg) s += ps[2048 + gg * 128 + c];
        partial[(size_t)blockIdx.x * 256 + 128 + c] = s;
    }
}

// ---------------- two-stage partial reduction -> stats[256] ----------------
__global__ __launch_bounds__(256) void stats_s1_kernel(const float* __restrict__ partial,
                                                       float* __restrict__ p2) {
    int t = threadIdx.x;
    float s = 0.f;
    for (int b = blockIdx.x; b < GEMM_NB; b += 32) s += partial[(size_t)b * 256 + t];
    p2[blockIdx.x * 256 + t] = s;
}

__global__ __launch_bounds__(256) void stats_s2_kernel(const float* __restrict__ p2,
                                                       float* __restrict__ stats) {
    int t = threadIdx.x;
    float s = 0.f;
    #pragma unroll
    for (int b = 0; b < 32; ++b) s += p2[b * 256 + t];
    stats[t] = s;
}

// ---------------- BN apply + ReLU; emit fp16 dn_out-scaled copy ----------------
__global__ __launch_bounds__(256) void bn_relu_scale_kernel(float* __restrict__ h,
                                                            __half* __restrict__ hs,
                                                            const float* __restrict__ stats,
                                                            const float* __restrict__ g,
                                                            const float* __restrict__ be,
                                                            const float* __restrict__ dn_out) {
    size_t idx = (size_t)blockIdx.x * 256 + threadIdx.x;
    if (idx >= (size_t)NODES * 32) return;
    int c = (int)(idx & 31) * 4;
    int row = (int)(idx >> 5);
    const float invN = 1.0f / NODES;
    float4 v = *(float4*)(h + idx * 4);
    float vv[4] = {v.x, v.y, v.z, v.w};
    float o[4];
    #pragma unroll
    for (int j = 0; j < 4; ++j) {
        float mu = stats[c + j] * invN;
        float var = stats[DIM + c + j] * invN - mu * mu;
        float w = g[c + j] * rsqrtf(var + EPS_BN);
        o[j] = fmaxf(w * (vv[j] - mu) + be[c + j], 0.f);
    }
    float4 r = {o[0], o[1], o[2], o[3]};
    *(float4*)(h + idx * 4) = r;
    float sc = dn_out[row];
    __half2 a = __floats2half2_rn(o[0] * sc, o[1] * sc);
    __half2 b = __floats2half2_rn(o[2] * sc, o[3] * sc);
    float2 rs;
    *(__half2*)&rs.x = a;
    *(__half2*)&rs.y = b;
    *(float2*)((char*)hs + idx * 8) = rs;
}

// ---------------- BN apply + residual + ReLU ----------------
__global__ __launch_bounds__(256) void bn_res_relu_kernel(float* __restrict__ out,
                                                          const float* __restrict__ h1,
                                                          const float* __restrict__ stats,
                                                          const float* __restrict__ g,
                                                          const float* __restrict__ be) {
    size_t idx = (size_t)blockIdx.x * 256 + threadIdx.x;
    if (idx >= (size_t)NODES * 32) return;
    int c = (int)(idx & 31) * 4;
    const float invN = 1.0f / NODES;
    float4 v = *(float4*)(out + idx * 4);
    float4 r1 = *(const float4*)(h1 + idx * 4);
    float vv[4] = {v.x, v.y, v.z, v.w};
    float rr[4] = {r1.x, r1.y, r1.z, r1.w};
    float o[4];
    #pragma unroll
    for (int j = 0; j < 4; ++j) {
        float mu = stats[c + j] * invN;
        float var = stats[DIM + c + j] * invN - mu * mu;
        float w = g[c + j] * rsqrtf(var + EPS_BN);
        o[j] = fmaxf(w * (vv[j] - mu) + be[c + j] + rr[j], 0.f);
    }
    float4 r = {o[0], o[1], o[2], o[3]};
    *(float4*)(out + idx * 4) = r;
}

extern "C" void kernel_launch(void* const* d_in, const int* in_sizes, int n_in,
                              void* d_out, int out_size, void* d_ws, size_t ws_size,
                              hipStream_t stream) {
    const float* x      = (const float*)d_in[0];
    const int*   src    = (const int*)d_in[1];
    const int*   dst    = (const int*)d_in[2];
    const float* W1     = (const float*)d_in[3];
    const float* b1     = (const float*)d_in[4];
    const float* gamma1 = (const float*)d_in[5];
    const float* beta1  = (const float*)d_in[6];
    const float* W2     = (const float*)d_in[7];
    const float* b2     = (const float*)d_in[8];
    const float* gamma2 = (const float*)d_in[9];
    const float* beta2  = (const float*)d_in[10];
    float* out = (float*)d_out;
    __half* hs = (__half*)d_out;   // fp16 pull-source scratch inside d_out

    char* wsc = (char*)d_ws;
    int*   cnt_in   = (int*)wsc;                     wsc += NODES * 4;
    float* dn_out   = (float*)wsc;                   wsc += NODES * 4;
    float* dn_in    = (float*)wsc;                   wsc += NODES * 4;
    int*   row_ptr  = (int*)wsc;                     wsc += (NODES + 1) * 4;
    int*   csr_src  = (int*)wsc;                     wsc += EDGES * 4;
    float* stats    = (float*)wsc;                   wsc += 2 * DIM * 4;
    int*   blk_sums = (int*)wsc;                     wsc += 64 * 4;
    int*   blk_off  = (int*)wsc;                     wsc += 64 * 4;
    __half* WhT1    = (__half*)wsc;                  wsc += DIM * DIM * 2;
    __half* WhT2    = (__half*)wsc;                  wsc += DIM * DIM * 2;
    float* partial  = (float*)wsc;                   wsc += (size_t)GEMM_NB * 256 * 4;
    float* p2       = (float*)wsc;                   wsc += 32 * 256 * 4;
    unsigned short* Psrc = (unsigned short*)wsc;     wsc += (size_t)NCH * NODES * 2;
    unsigned short* Pdst = (unsigned short*)wsc;     wsc += (size_t)NCH * NODES * 2;
    __half* agg     = (__half*)wsc;                  wsc += (size_t)NODES * DIM * 2;
    float* h1       = (float*)wsc;

    const int T = 256;
    const int grid_pull = (NODES + 3) / 4;
    const int grid_elem = (NODES * 32 + T - 1) / T;

    // graph prep — fully atomic-free (LDS atomics only)
    hist_part_kernel<<<dim3(NR * NCH, 2), T, 0, stream>>>(src, dst, Psrc, Pdst);
    combine_kernel<<<(NODES + T - 1) / T, T, 0, stream>>>(Psrc, Pdst, cnt_in, dn_out, dn_in);
    scan_p1_kernel<<<SCAN_NB, SCAN_B, 0, stream>>>(cnt_in, row_ptr, blk_sums);
    scan_p2_kernel<<<1, 64, 0, stream>>>(blk_sums, blk_off);
    scan_p3_kernel<<<SCAN_NB, SCAN_B, 0, stream>>>(row_ptr, blk_off);
    fill_kernel<<<NR * NCH, T, 0, stream>>>(src, dst, row_ptr, Pdst, csr_src);

    // weight conversion
    w2h_kernel<<<64, T, 0, stream>>>(W1, WhT1);
    w2h_kernel<<<64, T, 0, stream>>>(W2, WhT2);

    // layer 1
    prescale_kernel<<<grid_elem, T, 0, stream>>>(x, dn_out, hs);
    pull_kernel<<<grid_pull, T, 0, stream>>>(hs, row_ptr, csr_src, dn_in, agg);
    gemm_mfma_kernel<<<GEMM_NB, T, 0, stream>>>(agg, WhT1, b1, h1, partial);
    stats_s1_kernel<<<32, T, 0, stream>>>(partial, p2);
    stats_s2_kernel<<<1, T, 0, stream>>>(p2, stats);
    bn_relu_scale_kernel<<<grid_elem, T, 0, stream>>>(h1, hs, stats, gamma1, beta1, dn_out);

    // layer 2
    pull_kernel<<<grid_pull, T, 0, stream>>>(hs, row_ptr, csr_src, dn_in, agg);
    gemm_mfma_kernel<<<GEMM_NB, T, 0, stream>>>(agg, WhT2, b2, out, partial);
    stats_s1_kernel<<<32, T, 0, stream>>>(partial, p2);
    stats_s2_kernel<<<1, T, 0, stream>>>(p2, stats);
    bn_res_relu_kernel<<<grid_elem, T, 0, stream>>>(out, h1, stats, gamma2, beta2);
}

// Round 9
// 283.729 us; speedup vs baseline: 1.9879x; 1.0571x over previous
//
#include <hip/hip_runtime.h>
#include <hip/hip_fp16.h>

#define NODES 50000
#define EDGES 800000
#define DIM 128
#define EPS_BN 1e-5f
#define SCAN_B 1024
#define SCAN_NB ((NODES + SCAN_B - 1) / SCAN_B)   // 49
#define GEMM_NB ((NODES + 63) / 64)               // 782
#define NCH 64                                    // edge chunks
#define CHE (EDGES / NCH)                         // 12500 edges/chunk
#define NR 4                                      // node ranges
#define RNG (NODES / NR)                          // 12500 nodes/range

typedef _Float16 half8 __attribute__((ext_vector_type(8)));
typedef float floatx4 __attribute__((ext_vector_type(4)));

union H8 { half8 v; __half2 h2[4]; };

// ---------------- pass 1: partial LDS histograms (no global atomics) ----------------
__global__ __launch_bounds__(256) void hist_part_kernel(const int* __restrict__ src,
                                                        const int* __restrict__ dst,
                                                        unsigned short* __restrict__ Psrc,
                                                        unsigned short* __restrict__ Pdst) {
    __shared__ int h[RNG];   // 50 KB
    int chunk = blockIdx.x & (NCH - 1);
    int range = blockIdx.x >> 6;
    const int* arr = blockIdx.y ? dst : src;
    unsigned short* P = blockIdx.y ? Pdst : Psrc;
    int base = range * RNG;
    for (int i = threadIdx.x; i < RNG; i += 256) h[i] = 0;
    __syncthreads();
    int e0 = chunk * CHE;
    for (int e = e0 + threadIdx.x; e < e0 + CHE; e += 256) {
        unsigned r = (unsigned)(arr[e] - base);
        if (r < (unsigned)RNG) atomicAdd(&h[r], 1);
    }
    __syncthreads();
    for (int i = threadIdx.x; i < RNG; i += 256)
        P[(size_t)chunk * NODES + base + i] = (unsigned short)h[i];
}

// ---------------- pass 2: sum Psrc -> dn_out; scan Pdst in place -> bases, cnt_in ----
__global__ __launch_bounds__(256) void combine_kernel(const unsigned short* __restrict__ Psrc,
                                                      unsigned short* __restrict__ Pdst,
                                                      int* __restrict__ cnt_in,
                                                      float* __restrict__ dn_out,
                                                      float* __restrict__ dn_in) {
    int v = blockIdx.x * 256 + threadIdx.x;
    if (v >= NODES) return;
    int s = 0;
    #pragma unroll 8
    for (int j = 0; j < NCH; ++j) s += Psrc[(size_t)j * NODES + v];
    dn_out[v] = rsqrtf((float)max(s, 1));
    int run = 0;
    for (int j = 0; j < NCH; ++j) {
        int t = Pdst[(size_t)j * NODES + v];
        Pdst[(size_t)j * NODES + v] = (unsigned short)run;
        run += t;
    }
    cnt_in[v] = run;
    dn_in[v] = rsqrtf((float)max(run, 1));
}

// ---------------- row_ptr scan over cnt_in ----------------
__global__ __launch_bounds__(SCAN_B) void scan_p1_kernel(const int* __restrict__ cnt,
                                                         int* __restrict__ row_ptr,
                                                         int* __restrict__ blk_sums) {
    __shared__ int sm[SCAN_B];
    int t = threadIdx.x;
    int idx = blockIdx.x * SCAN_B + t;
    int v = (idx < NODES) ? cnt[idx] : 0;
    sm[t] = v;
    __syncthreads();
    #pragma unroll
    for (int off = 1; off < SCAN_B; off <<= 1) {
        int u = (t >= off) ? sm[t - off] : 0;
        __syncthreads();
        sm[t] += u;
        __syncthreads();
    }
    if (idx < NODES) row_ptr[idx] = sm[t] - v;
    if (t == SCAN_B - 1) blk_sums[blockIdx.x] = sm[t];
}

// p3 with fused block-offset computation: wave-reduce blk_sums[0..blockIdx.x)
__global__ __launch_bounds__(SCAN_B) void scan_p3_kernel(int* __restrict__ row_ptr,
                                                         const int* __restrict__ blk_sums) {
    __shared__ int soff;
    int t = threadIdx.x;
    if (t < 64) {
        int v = (t < blockIdx.x) ? blk_sums[t] : 0;
        #pragma unroll
        for (int off = 32; off > 0; off >>= 1) v += __shfl_xor(v, off);
        if (t == 0) soff = v;
    }
    __syncthreads();
    int idx = blockIdx.x * SCAN_B + t;
    if (idx < NODES) row_ptr[idx] += soff;
    if (idx == 0) row_ptr[NODES] = EDGES;
}

// ---------------- pass 3: CSR fill via local re-histogram ----------------
__global__ __launch_bounds__(256) void fill_kernel(const int* __restrict__ src,
                                                   const int* __restrict__ dst,
                                                   const int* __restrict__ row_ptr,
                                                   const unsigned short* __restrict__ Pdst,
                                                   int* __restrict__ csr_src) {
    __shared__ int h[RNG];   // 50 KB
    int chunk = blockIdx.x & (NCH - 1);
    int range = blockIdx.x >> 6;
    int base = range * RNG;
    for (int i = threadIdx.x; i < RNG; i += 256) h[i] = 0;
    __syncthreads();
    int e0 = chunk * CHE;
    const unsigned short* Pj = Pdst + (size_t)chunk * NODES;
    for (int e = e0 + threadIdx.x; e < e0 + CHE; e += 256) {
        int d = dst[e];
        unsigned r = (unsigned)(d - base);
        if (r < (unsigned)RNG) {
            int local = atomicAdd(&h[r], 1);   // LDS atomic only
            csr_src[row_ptr[d] + (int)Pj[d] + local] = src[e];
        }
    }
}

// ---------------- W1+W2 fp32 -> fp16 transposed (one kernel) ----------------
__global__ __launch_bounds__(256) void w2h_kernel(const float* __restrict__ W1,
                                                  const float* __restrict__ W2,
                                                  __half* __restrict__ WhT1,
                                                  __half* __restrict__ WhT2) {
    int idx = blockIdx.x * 256 + threadIdx.x;   // 32768 total
    const float* W = (idx < 16384) ? W1 : W2;
    __half* D = (idx < 16384) ? WhT1 : WhT2;
    int i = idx & 16383;
    int n = i >> 7;
    int k = i & 127;
    D[i] = __float2half(W[k * DIM + n]);        // D[n][k] = W[k][n]
}

// ---------------- prescale to fp16: 8 cols/thread ----------------
__global__ __launch_bounds__(256) void prescale_kernel(const float* __restrict__ x,
                                                       const float* __restrict__ dn_out,
                                                       __half* __restrict__ hs) {
    int idx = blockIdx.x * 256 + threadIdx.x;   // over N*16
    if (idx >= NODES * 16) return;
    int row = idx >> 4;
    int c8 = (idx & 15) * 8;
    float sc = dn_out[row];
    const float* xp = x + (size_t)row * DIM + c8;
    float4 v0 = *(const float4*)xp;
    float4 v1 = *(const float4*)(xp + 4);
    H8 u;
    u.h2[0] = __floats2half2_rn(v0.x * sc, v0.y * sc);
    u.h2[1] = __floats2half2_rn(v0.z * sc, v0.w * sc);
    u.h2[2] = __floats2half2_rn(v1.x * sc, v1.y * sc);
    u.h2[3] = __floats2half2_rn(v1.z * sc, v1.w * sc);
    *(half8*)((char*)hs + ((size_t)row * DIM + c8) * 2) = u.v;
}

// ---------------- pull: 16 lanes x 16 B per edge, 4 edge slots/wave ----------------
__device__ __forceinline__ void acc_h8(half8 raw, float* a) {
    H8 u; u.v = raw;
    #pragma unroll
    for (int k = 0; k < 4; ++k) {
        float2 f = __half22float2(u.h2[k]);
        a[2 * k] += f.x;
        a[2 * k + 1] += f.y;
    }
}

__global__ __launch_bounds__(256) void pull_kernel(const __half* __restrict__ hs,
                                                   const int* __restrict__ row_ptr,
                                                   const int* __restrict__ csr_src,
                                                   const float* __restrict__ dn_in,
                                                   __half* __restrict__ agg) {
    int wid = threadIdx.x >> 6;
    int node = blockIdx.x * 4 + wid;
    if (node >= NODES) return;
    int lane = threadIdx.x & 63;
    int q = lane >> 4;        // edge slot 0..3
    int c = lane & 15;        // 16-B chunk within row
    const char* base = (const char*)hs;
    int beg = row_ptr[node];
    int end = row_ptr[node + 1];
    float a[8];
    #pragma unroll
    for (int i = 0; i < 8; ++i) a[i] = 0.f;
    int eb = beg;
    for (; eb + 8 <= end; eb += 8) {
        int s0 = csr_src[eb + q];
        int s1 = csr_src[eb + 4 + q];
        half8 v0 = *(const half8*)(base + (size_t)s0 * 256 + c * 16);
        half8 v1 = *(const half8*)(base + (size_t)s1 * 256 + c * 16);
        acc_h8(v0, a);
        acc_h8(v1, a);
    }
    for (; eb + 4 <= end; eb += 4) {
        int s0 = csr_src[eb + q];
        half8 v0 = *(const half8*)(base + (size_t)s0 * 256 + c * 16);
        acc_h8(v0, a);
    }
    if (eb + q < end) {
        int s0 = csr_src[eb + q];
        half8 v0 = *(const half8*)(base + (size_t)s0 * 256 + c * 16);
        acc_h8(v0, a);
    }
    #pragma unroll
    for (int i = 0; i < 8; ++i) a[i] += __shfl_xor(a[i], 32);
    #pragma unroll
    for (int i = 0; i < 8; ++i) a[i] += __shfl_xor(a[i], 16);
    if (lane < 16) {
        float sc = dn_in[node];
        H8 u;
        #pragma unroll
        for (int k = 0; k < 4; ++k)
            u.h2[k] = __floats2half2_rn(a[2 * k] * sc, a[2 * k + 1] * sc);
        *(half8*)((char*)agg + (size_t)node * 256 + c * 16) = u.v;
    }
}

// ---------------- MFMA GEMM (fp16 in/out) + fused BN partial stats ----------------
__global__ __launch_bounds__(256) void gemm_mfma_kernel(const __half* __restrict__ A,
                                                        const __half* __restrict__ WhT,
                                                        const float* __restrict__ bias,
                                                        __half* __restrict__ hraw,
                                                        float* __restrict__ partial) {
    __shared__ float smem[8704];
    __half* wl = (__half*)smem;

    int t = threadIdx.x;

    #pragma unroll
    for (int i = 0; i < 8; ++i) {
        int cch = t + 256 * i;
        int n = cch >> 4;
        int ch = cch & 15;
        *(float4*)((char*)wl + n * 272 + ch * 16) =
            *(const float4*)((const char*)WhT + n * 256 + ch * 16);
    }

    int w = t >> 6;
    int lane = t & 63;
    int m = lane & 15;
    int quad = lane >> 4;
    int r0 = blockIdx.x * 64 + w * 16;
    int arow = r0 + m;

    half8 afrag[4];
    if (arow < NODES) {
        const char* ap = (const char*)(A + (size_t)arow * DIM);
        #pragma unroll
        for (int kt = 0; kt < 4; ++kt)
            afrag[kt] = *(const half8*)(ap + kt * 64 + quad * 16);
    } else {
        #pragma unroll
        for (int kt = 0; kt < 4; ++kt)
            #pragma unroll
            for (int j = 0; j < 8; ++j)
                afrag[kt][j] = (_Float16)0.0f;
    }

    floatx4 acc[8];
    floatx4 zf = {0.f, 0.f, 0.f, 0.f};
    #pragma unroll
    for (int ct = 0; ct < 8; ++ct) acc[ct] = zf;

    __syncthreads();

    #pragma unroll
    for (int kt = 0; kt < 4; ++kt) {
        #pragma unroll
        for (int ct = 0; ct < 8; ++ct) {
            half8 b = *(const half8*)((const char*)wl + (ct * 16 + m) * 272 + kt * 64 + quad * 16);
            acc[ct] = __builtin_amdgcn_mfma_f32_16x16x32_f16(afrag[kt], b, acc[ct], 0, 0, 0);
        }
    }

    __syncthreads();

    float* ps = smem;
    int g = w * 4 + quad;
    #pragma unroll
    for (int ct = 0; ct < 8; ++ct) {
        int col = ct * 16 + m;
        float bb = bias[col];
        float cs = 0.f, cq = 0.f;
        #pragma unroll
        for (int reg = 0; reg < 4; ++reg) {
            int row = r0 + quad * 4 + reg;
            if (row < NODES) {
                float o = acc[ct][reg] + bb;
                hraw[(size_t)row * DIM + col] = __float2half(o);
                cs += o;
                cq += o * o;
            }
        }
        ps[g * 128 + col] = cs;
        ps[2048 + g * 128 + col] = cq;
    }
    __syncthreads();

    if (t < 128) {
        float s = 0.f;
        #pragma unroll
        for (int gg = 0; gg < 16; ++gg) s += ps[gg * 128 + t];
        partial[(size_t)blockIdx.x * 256 + t] = s;
    } else {
        int cc = t - 128;
        float s = 0.f;
        #pragma unroll
        for (int gg = 0; gg < 16; ++gg) s += ps[2048 + gg * 128 + cc];
        partial[(size_t)blockIdx.x * 256 + 128 + cc] = s;
    }
}

// ---------------- two-stage partial reduction -> stats[256] ----------------
__global__ __launch_bounds__(256) void stats_s1_kernel(const float* __restrict__ partial,
                                                       float* __restrict__ p2) {
    int t = threadIdx.x;
    float s = 0.f;
    for (int b = blockIdx.x; b < GEMM_NB; b += 32) s += partial[(size_t)b * 256 + t];
    p2[blockIdx.x * 256 + t] = s;
}

__global__ __launch_bounds__(256) void stats_s2_kernel(const float* __restrict__ p2,
                                                       float* __restrict__ stats) {
    int t = threadIdx.x;
    float s = 0.f;
    #pragma unroll
    for (int b = 0; b < 32; ++b) s += p2[b * 256 + t];
    stats[t] = s;
}

// ---------------- BN apply + ReLU (fp16 in) -> h1r fp16 + hs fp16 ----------------
__global__ __launch_bounds__(256) void bn_relu_scale_kernel(const __half* __restrict__ hraw,
                                                            __half* __restrict__ h1r,
                                                            __half* __restrict__ hs,
                                                            const float* __restrict__ stats,
                                                            const float* __restrict__ g,
                                                            const float* __restrict__ be,
                                                            const float* __restrict__ dn_out) {
    int idx = blockIdx.x * 256 + threadIdx.x;   // over N*16
    if (idx >= NODES * 16) return;
    int row = idx >> 4;
    int c8 = (idx & 15) * 8;
    const float invN = 1.0f / NODES;
    H8 u;
    u.v = *(const half8*)((const char*)hraw + ((size_t)row * DIM + c8) * 2);
    float o[8];
    #pragma unroll
    for (int k = 0; k < 4; ++k) {
        float2 f = __half22float2(u.h2[k]);
        o[2 * k] = f.x;
        o[2 * k + 1] = f.y;
    }
    #pragma unroll
    for (int j = 0; j < 8; ++j) {
        int cj = c8 + j;
        float mu = stats[cj] * invN;
        float var = stats[DIM + cj] * invN - mu * mu;
        float w = g[cj] * rsqrtf(var + EPS_BN);
        o[j] = fmaxf(w * (o[j] - mu) + be[cj], 0.f);
    }
    H8 ur, us;
    float sc = dn_out[row];
    #pragma unroll
    for (int k = 0; k < 4; ++k) {
        ur.h2[k] = __floats2half2_rn(o[2 * k], o[2 * k + 1]);
        us.h2[k] = __floats2half2_rn(o[2 * k] * sc, o[2 * k + 1] * sc);
    }
    *(half8*)((char*)h1r + ((size_t)row * DIM + c8) * 2) = ur.v;
    *(half8*)((char*)hs + ((size_t)row * DIM + c8) * 2) = us.v;
}

// ---------------- BN apply + residual + ReLU -> out fp32 ----------------
__global__ __launch_bounds__(256) void bn_res_relu_kernel(const __half* __restrict__ hraw,
                                                          const __half* __restrict__ h1r,
                                                          float* __restrict__ out,
                                                          const float* __restrict__ stats,
                                                          const float* __restrict__ g,
                                                          const float* __restrict__ be) {
    int idx = blockIdx.x * 256 + threadIdx.x;   // over N*16
    if (idx >= NODES * 16) return;
    int row = idx >> 4;
    int c8 = (idx & 15) * 8;
    const float invN = 1.0f / NODES;
    H8 u, ur;
    u.v = *(const half8*)((const char*)hraw + ((size_t)row * DIM + c8) * 2);
    ur.v = *(const half8*)((const char*)h1r + ((size_t)row * DIM + c8) * 2);
    float o[8], r[8];
    #pragma unroll
    for (int k = 0; k < 4; ++k) {
        float2 f = __half22float2(u.h2[k]);
        float2 fr = __half22float2(ur.h2[k]);
        o[2 * k] = f.x; o[2 * k + 1] = f.y;
        r[2 * k] = fr.x; r[2 * k + 1] = fr.y;
    }
    #pragma unroll
    for (int j = 0; j < 8; ++j) {
        int cj = c8 + j;
        float mu = stats[cj] * invN;
        float var = stats[DIM + cj] * invN - mu * mu;
        float w = g[cj] * rsqrtf(var + EPS_BN);
        o[j] = fmaxf(w * (o[j] - mu) + be[cj] + r[j], 0.f);
    }
    float* op = out + (size_t)row * DIM + c8;
    float4 o0 = {o[0], o[1], o[2], o[3]};
    float4 o1 = {o[4], o[5], o[6], o[7]};
    *(float4*)op = o0;
    *(float4*)(op + 4) = o1;
}

extern "C" void kernel_launch(void* const* d_in, const int* in_sizes, int n_in,
                              void* d_out, int out_size, void* d_ws, size_t ws_size,
                              hipStream_t stream) {
    const float* x      = (const float*)d_in[0];
    const int*   src    = (const int*)d_in[1];
    const int*   dst    = (const int*)d_in[2];
    const float* W1     = (const float*)d_in[3];
    const float* b1     = (const float*)d_in[4];
    const float* gamma1 = (const float*)d_in[5];
    const float* beta1  = (const float*)d_in[6];
    const float* W2     = (const float*)d_in[7];
    const float* b2     = (const float*)d_in[8];
    const float* gamma2 = (const float*)d_in[9];
    const float* beta2  = (const float*)d_in[10];
    float* out = (float*)d_out;
    __half* hs = (__half*)d_out;   // fp16 pull-source scratch inside d_out
                                   // (consumed by pull-2 before bn2 writes out)

    char* wsc = (char*)d_ws;
    int*   cnt_in   = (int*)wsc;                     wsc += NODES * 4;
    float* dn_out   = (float*)wsc;                   wsc += NODES * 4;
    float* dn_in    = (float*)wsc;                   wsc += NODES * 4;
    int*   row_ptr  = (int*)wsc;                     wsc += (NODES + 1) * 4;
    int*   csr_src  = (int*)wsc;                     wsc += EDGES * 4;
    float* stats    = (float*)wsc;                   wsc += 2 * DIM * 4;
    int*   blk_sums = (int*)wsc;                     wsc += 64 * 4;
    __half* WhT1    = (__half*)wsc;                  wsc += DIM * DIM * 2;
    __half* WhT2    = (__half*)wsc;                  wsc += DIM * DIM * 2;
    float* partial  = (float*)wsc;                   wsc += (size_t)GEMM_NB * 256 * 4;
    float* p2       = (float*)wsc;                   wsc += 32 * 256 * 4;
    unsigned short* Psrc = (unsigned short*)wsc;     wsc += (size_t)NCH * NODES * 2;
    unsigned short* Pdst = (unsigned short*)wsc;     wsc += (size_t)NCH * NODES * 2;
    __half* agg     = (__half*)wsc;                  wsc += (size_t)NODES * DIM * 2;
    __half* hraw    = (__half*)wsc;                  wsc += (size_t)NODES * DIM * 2;
    __half* h1r     = (__half*)wsc;                  wsc += (size_t)NODES * DIM * 2;

    const int T = 256;
    const int grid_pull = (NODES + 3) / 4;
    const int grid_e16  = (NODES * 16 + T - 1) / T;

    // graph prep — fully atomic-free (LDS atomics only)
    hist_part_kernel<<<dim3(NR * NCH, 2), T, 0, stream>>>(src, dst, Psrc, Pdst);
    combine_kernel<<<(NODES + T - 1) / T, T, 0, stream>>>(Psrc, Pdst, cnt_in, dn_out, dn_in);
    scan_p1_kernel<<<SCAN_NB, SCAN_B, 0, stream>>>(cnt_in, row_ptr, blk_sums);
    scan_p3_kernel<<<SCAN_NB, SCAN_B, 0, stream>>>(row_ptr, blk_sums);
    fill_kernel<<<NR * NCH, T, 0, stream>>>(src, dst, row_ptr, Pdst, csr_src);

    // weight conversion (both in one kernel)
    w2h_kernel<<<128, T, 0, stream>>>(W1, W2, WhT1, WhT2);

    // layer 1
    prescale_kernel<<<grid_e16, T, 0, stream>>>(x, dn_out, hs);
    pull_kernel<<<grid_pull, T, 0, stream>>>(hs, row_ptr, csr_src, dn_in, agg);
    gemm_mfma_kernel<<<GEMM_NB, T, 0, stream>>>(agg, WhT1, b1, hraw, partial);
    stats_s1_kernel<<<32, T, 0, stream>>>(partial, p2);
    stats_s2_kernel<<<1, T, 0, stream>>>(p2, stats);
    bn_relu_scale_kernel<<<grid_e16, T, 0, stream>>>(hraw, h1r, hs, stats, gamma1, beta1, dn_out);

    // layer 2
    pull_kernel<<<grid_pull, T, 0, stream>>>(hs, row_ptr, csr_src, dn_in, agg);
    gemm_mfma_kernel<<<GEMM_NB, T, 0, stream>>>(agg, WhT2, b2, hraw, partial);
    stats_s1_kernel<<<32, T, 0, stream>>>(partial, p2);
    stats_s2_kernel<<<1, T, 0, stream>>>(p2, stats);
    bn_res_relu_kernel<<<grid_e16, T, 0, stream>>>(hraw, h1r, out, stats, gamma2, beta2);
}